// Round 3
// baseline (170.318 us; speedup 1.0000x reference)
//
#include <hip/hip_runtime.h>
#include <math.h>

// Chamfer distance via MFMA: d2[n,m] = a(n)·b(m) with augmented 5-vectors
//   a = (qx,qy,qz,|q|^2,1), b = (-2px,-2py,-2pz,1,|p|^2)
// computed at fp32 precision through a 3-way bf16 split (Ootomo):
//   a = a1+a2+a3, products {a1b1,a1b2,a2b1,a1b3,a3b1,a2b2} packed along K:
//   6 groups x 5 dims = 30 <= K=32  ->  ONE v_mfma_f32_16x16x32_bf16 per
//   16x16 d2 tile (dropped terms <= 2^-24 relative).
// B=16, N=2048 samp (rows), M=8192 ref (cols), fp32 in/out.
//
// v4 vs v3 (106.8 us): sweep moved from VALU (54 us, MfmaUtil=0) to MFMA pipe.
#define BB 16
#define NN 2048
#define MM 8192

#define TN 128                 // query rows per block (4 waves x 32)
#define TM 512                 // ref cols per block (LDS tile 32 KB)
#define BLK 256

typedef __attribute__((ext_vector_type(8))) short short8;
typedef __attribute__((ext_vector_type(4))) float f32x4;

union U16 { uint4 u; short8 s; };

// ---- bf16 3-way split helpers (round-to-nearest-even) ----
static __device__ __forceinline__ unsigned short f2bf(float f) {
    unsigned int u = __float_as_uint(f);
    unsigned int r = (u + 0x7FFFu + ((u >> 16) & 1u)) >> 16;
    return (unsigned short)r;
}
static __device__ __forceinline__ float bf2f(unsigned short h) {
    return __uint_as_float(((unsigned int)h) << 16);
}

// ws layout:
//   ws2 : uint[BB*MM]        ref->samp mins (atomicMin, memset 0x7F)  512 KB
//   ws1 : uint[BB*NN]        samp->ref mins (atomicMin, memset 0x7F)  128 KB
//   Apk : ushort[BB*NN*32]   query K-major bf16 frags (64 B/point)      2 MB
//   Bpk : ushort[BB*MM*32]   ref K-major bf16 frags, chunk-swizzled     8 MB
// total 10.625 MB

// Build the packed K-layouts. A groups: {1,1,2,1,3,2}; B groups: {1,2,1,3,1,2}.
// B chunks (16B) are stored at (g ^ ((m>>1)&3)) so a LINEAR global->LDS copy
// yields a bank-conflict-free ds_read_b128 fragment pattern in sweep.
__global__ void __launch_bounds__(BLK) prep_kernel(const float* __restrict__ ref,
                                                   const float* __restrict__ samp,
                                                   unsigned short* __restrict__ Apk,
                                                   unsigned short* __restrict__ Bpk) {
    const int i = blockIdx.x * BLK + threadIdx.x;
    const int PN = BB * NN;
    float a5[5];
    unsigned short h[3][5];
    unsigned short K[32];

    if (i < PN) {
        const float* s0 = samp + (size_t)i * 3;
        float x = s0[0], y = s0[1], z = s0[2];
        a5[0] = x; a5[1] = y; a5[2] = z;
        a5[3] = fmaf(x, x, fmaf(y, y, z * z)); a5[4] = 1.f;
#pragma unroll
        for (int j = 0; j < 5; ++j) {
            float v = a5[j];
            h[0][j] = f2bf(v); float r1 = v - bf2f(h[0][j]);
            h[1][j] = f2bf(r1); float r2 = r1 - bf2f(h[1][j]);
            h[2][j] = f2bf(r2);
        }
        const int ordA[6] = {0, 0, 1, 0, 2, 1};
#pragma unroll
        for (int t = 0; t < 6; ++t)
#pragma unroll
            for (int j = 0; j < 5; ++j) K[t * 5 + j] = h[ordA[t]][j];
        K[30] = 0; K[31] = 0;
        unsigned int uu[16];
#pragma unroll
        for (int t = 0; t < 16; ++t)
            uu[t] = (unsigned int)K[2 * t] | ((unsigned int)K[2 * t + 1] << 16);
        uint4* dst = (uint4*)(Apk + (size_t)i * 32);
        dst[0] = make_uint4(uu[0], uu[1], uu[2], uu[3]);
        dst[1] = make_uint4(uu[4], uu[5], uu[6], uu[7]);
        dst[2] = make_uint4(uu[8], uu[9], uu[10], uu[11]);
        dst[3] = make_uint4(uu[12], uu[13], uu[14], uu[15]);
    } else if (i < PN + BB * MM) {
        const int j = i - PN;
        const int m = j & (MM - 1);
        const float* r0 = ref + (size_t)j * 3;
        float x = r0[0], y = r0[1], z = r0[2];
        a5[0] = -2.f * x; a5[1] = -2.f * y; a5[2] = -2.f * z;
        a5[3] = 1.f; a5[4] = fmaf(x, x, fmaf(y, y, z * z));
#pragma unroll
        for (int jj = 0; jj < 5; ++jj) {
            float v = a5[jj];
            h[0][jj] = f2bf(v); float r1 = v - bf2f(h[0][jj]);
            h[1][jj] = f2bf(r1); float r2 = r1 - bf2f(h[1][jj]);
            h[2][jj] = f2bf(r2);
        }
        const int ordB[6] = {0, 1, 0, 2, 0, 1};
#pragma unroll
        for (int t = 0; t < 6; ++t)
#pragma unroll
            for (int jj = 0; jj < 5; ++jj) K[t * 5 + jj] = h[ordB[t]][jj];
        K[30] = 0; K[31] = 0;
        unsigned int uu[16];
#pragma unroll
        for (int t = 0; t < 16; ++t)
            uu[t] = (unsigned int)K[2 * t] | ((unsigned int)K[2 * t + 1] << 16);
        uint4 c0 = make_uint4(uu[0], uu[1], uu[2], uu[3]);
        uint4 c1 = make_uint4(uu[4], uu[5], uu[6], uu[7]);
        uint4 c2 = make_uint4(uu[8], uu[9], uu[10], uu[11]);
        uint4 c3 = make_uint4(uu[12], uu[13], uu[14], uu[15]);
        uint4* dst = (uint4*)(Bpk + (size_t)j * 32);
        const int s = (m >> 1) & 3;                       // bank-quad swizzle
        dst[0 ^ s] = c0; dst[1 ^ s] = c1; dst[2 ^ s] = c2; dst[3 ^ s] = c3;
    }
}

// grid = (B, N/TN, M/TM) = (16,16,16) = 4096 blocks, 4 waves.
// Wave w: rows [n0+32w, n0+32w+32) x all TM cols. Per ct (16-col tile):
// 1 ds_read_b128 B-frag + 2 MFMA (row-tiles) + min trees + 2 shfl + 1 atomic.
__global__ void __launch_bounds__(BLK, 4) sweep_kernel(const unsigned short* __restrict__ Apk,
                                                       const unsigned short* __restrict__ Bpk,
                                                       unsigned int* __restrict__ ws2,
                                                       unsigned int* __restrict__ ws1) {
    __shared__ uint4 Bt[TM * 4];                          // 32 KB ref tile

    const int b = blockIdx.x;
    const int n0 = blockIdx.y * TN;
    const int m0 = blockIdx.z * TM;
    const int tid = threadIdx.x;
    const int w = tid >> 6;
    const int l = tid & 63;
    const int r = l & 15;                                 // frag row/col lane
    const int g = l >> 4;                                 // k-octet group

    // stage B tile (linear copy; swizzle already baked into Bpk)
    const uint4* bs = (const uint4*)(Bpk + ((size_t)(b * MM + m0)) * 32);
#pragma unroll
    for (int k = 0; k < (TM * 4) / BLK; ++k) Bt[tid + k * BLK] = bs[tid + k * BLK];

    // A fragments direct from global (L2-hot, 1 KB/wave-load, coalesced)
    const uint4* ap = (const uint4*)(Apk + ((size_t)(b * NN + n0 + w * 32)) * 32);
    U16 a0, a1;
    a0.u = ap[(r << 2) + g];
    a1.u = ap[64 + (r << 2) + g];
    __syncthreads();

    float qa0 = INFINITY, qa1 = INFINITY, qa2 = INFINITY, qa3 = INFINITY;
    float qb0 = INFINITY, qb1 = INFINITY, qb2 = INFINITY, qb3 = INFINITY;

    const uint4* bp = Bt + (r << 2) + (g ^ ((r >> 1) & 3));   // conflict-free
    unsigned int* w2 = ws2 + (size_t)b * MM + m0;
    const f32x4 fz = {0.f, 0.f, 0.f, 0.f};

#pragma unroll 4
    for (int ct = 0; ct < TM / 16; ++ct) {
        U16 bu; bu.u = bp[ct * 64];                       // ds_read_b128
        f32x4 d0 = __builtin_amdgcn_mfma_f32_16x16x32_bf16(a0.s, bu.s, fz, 0, 0, 0);
        f32x4 d1 = __builtin_amdgcn_mfma_f32_16x16x32_bf16(a1.s, bu.s, fz, 0, 0, 0);
        // query-direction running mins (rows fixed per lane: g*4+i / 16+g*4+i)
        qa0 = fminf(qa0, d0[0]); qa1 = fminf(qa1, d0[1]);
        qa2 = fminf(qa2, d0[2]); qa3 = fminf(qa3, d0[3]);
        qb0 = fminf(qb0, d1[0]); qb1 = fminf(qb1, d1[1]);
        qb2 = fminf(qb2, d1[2]); qb3 = fminf(qb3, d1[3]);
        // ref-direction: min over this wave's 32 rows for col = m0+ct*16+r
        float rm = fminf(fminf(fminf(d0[0], d0[1]), fminf(d0[2], d0[3])),
                         fminf(fminf(d1[0], d1[1]), fminf(d1[2], d1[3])));
        rm = fminf(rm, __shfl_xor(rm, 16));
        rm = fminf(rm, __shfl_xor(rm, 32));
        if (g == 0)
            atomicMin(&w2[ct * 16 + r], __float_as_uint(fmaxf(rm, 0.f)));
    }

    // query-direction: combine across the 16 col-lanes, then atomicMin
#pragma unroll
    for (int s = 1; s <= 8; s <<= 1) {
        qa0 = fminf(qa0, __shfl_xor(qa0, s));
        qa1 = fminf(qa1, __shfl_xor(qa1, s));
        qa2 = fminf(qa2, __shfl_xor(qa2, s));
        qa3 = fminf(qa3, __shfl_xor(qa3, s));
        qb0 = fminf(qb0, __shfl_xor(qb0, s));
        qb1 = fminf(qb1, __shfl_xor(qb1, s));
        qb2 = fminf(qb2, __shfl_xor(qb2, s));
        qb3 = fminf(qb3, __shfl_xor(qb3, s));
    }
    if (r == 0) {
        unsigned int* w1 = ws1 + (size_t)b * NN + n0 + w * 32 + g * 4;
        atomicMin(&w1[0],  __float_as_uint(fmaxf(qa0, 0.f)));
        atomicMin(&w1[1],  __float_as_uint(fmaxf(qa1, 0.f)));
        atomicMin(&w1[2],  __float_as_uint(fmaxf(qa2, 0.f)));
        atomicMin(&w1[3],  __float_as_uint(fmaxf(qa3, 0.f)));
        atomicMin(&w1[16], __float_as_uint(fmaxf(qb0, 0.f)));
        atomicMin(&w1[17], __float_as_uint(fmaxf(qb1, 0.f)));
        atomicMin(&w1[18], __float_as_uint(fmaxf(qb2, 0.f)));
        atomicMin(&w1[19], __float_as_uint(fmaxf(qb3, 0.f)));
    }
}

// Final reduce. grid = B, block = 1024. Wave shuffle-reduce + one LDS pass.
#define BLKR 1024
__global__ void __launch_bounds__(BLKR) reduce_kernel(const unsigned int* __restrict__ ws1,
                                                      const unsigned int* __restrict__ ws2,
                                                      float* __restrict__ out) {
    const int b = blockIdx.x;
    const int tid = threadIdx.x;
    const int lane = tid & 63;
    const int wv = tid >> 6;

    float sd1 = 0.f, sr1 = 0.f, sd2 = 0.f, sr2 = 0.f;
#pragma unroll
    for (int i = tid; i < NN; i += BLKR) {
        float v = __uint_as_float(ws1[(size_t)b * NN + i]);  // already >= 0
        sd1 += v;
        sr1 += sqrtf(v);
    }
#pragma unroll
    for (int i = tid; i < MM; i += BLKR) {
        float v = __uint_as_float(ws2[(size_t)b * MM + i]);  // already >= 0
        sd2 += v;
        sr2 += sqrtf(v);
    }
#pragma unroll
    for (int s = 32; s > 0; s >>= 1) {
        sd1 += __shfl_xor(sd1, s);
        sr1 += __shfl_xor(sr1, s);
        sd2 += __shfl_xor(sd2, s);
        sr2 += __shfl_xor(sr2, s);
    }

    __shared__ float4 red[BLKR / 64];
    if (lane == 0) red[wv] = make_float4(sd1, sr1, sd2, sr2);
    __syncthreads();
    if (tid == 0) {
        float4 acc = red[0];
#pragma unroll
        for (int w = 1; w < BLKR / 64; ++w) {
            acc.x += red[w].x; acc.y += red[w].y;
            acc.z += red[w].z; acc.w += red[w].w;
        }
        out[b]      = (acc.y * (1.0f / NN) + acc.w * (1.0f / MM)) * 0.5f;  // cd_p
        out[BB + b] = acc.x * (1.0f / NN) + acc.z * (1.0f / MM);           // cd_t
    }
}

extern "C" void kernel_launch(void* const* d_in, const int* in_sizes, int n_in,
                              void* d_out, int out_size, void* d_ws, size_t ws_size,
                              hipStream_t stream) {
    const float* ref  = (const float*)d_in[0];   // [B, M, 3]
    const float* samp = (const float*)d_in[1];   // [B, N, 3]
    float* out = (float*)d_out;                  // [cd_p[16], cd_t[16]]

    unsigned int* ws2 = (unsigned int*)d_ws;                        // BB*MM
    unsigned int* ws1 = ws2 + (size_t)BB * MM;                      // BB*NN
    unsigned short* Apk = (unsigned short*)(ws1 + (size_t)BB * NN); // BB*NN*32
    unsigned short* Bpk = Apk + (size_t)BB * NN * 32;               // BB*MM*32

    // 0x7F7F7F7F = 3.39e38 as float: +inf stand-in for uint-ordered atomicMin
    // over non-negative float bit patterns.
    hipMemsetAsync(d_ws, 0x7F, ((size_t)BB * MM + (size_t)BB * NN) * sizeof(unsigned int), stream);

    const int P = BB * (NN + MM);
    prep_kernel<<<P / BLK, BLK, 0, stream>>>(ref, samp, Apk, Bpk);

    dim3 gs(BB, NN / TN, MM / TM);   // (16, 16, 16) = 4096 blocks
    sweep_kernel<<<gs, BLK, 0, stream>>>(Apk, Bpk, ws2, ws1);

    reduce_kernel<<<BB, BLKR, 0, stream>>>(ws1, ws2, out);
}

// Round 4
// 103.093 us; speedup vs baseline: 1.6521x; 1.6521x over previous
//
#include <hip/hip_runtime.h>
#include <math.h>

// Chamfer distance via MFMA: d2[n,m] = a(n)·b(m) with augmented 5-vectors
//   a = (qx,qy,qz,|q|^2,1), b = (-2px,-2py,-2pz,1,|p|^2)
// computed at fp32 precision through a 3-way bf16 split (Ootomo):
//   a = a1+a2+a3, products {a1b1,a1b2,a2b1,a1b3,a3b1,a2b2} packed along K:
//   6 groups x 5 dims = 30 <= K=32  ->  ONE v_mfma_f32_16x16x32_bf16 per
//   16x16 d2 tile (dropped terms <= 2^-24 relative). Verified absmax = 0.0.
// B=16, N=2048 samp (rows), M=8192 ref (cols), fp32 in/out.
//
// v5 vs v4 (170 us; sweep 108 us, latency-bound at ~500 cyc/iter):
//  - inner loop stripped to fire-and-forget: the per-ct serial chain
//    (min tree -> 2x shfl_xor [DS latency] -> global atomicMin) prevented
//    software pipelining (VGPR=44 => one iteration in flight). Now: per-ct
//    ref-dir partial min goes to a per-block LDS colMin[] via ds atomicMin
//    (no return value => no dependency chain); cross-lane + cross-wave
//    merging happens in LDS; ONE global atomicMin per col per block in the
//    epilogue (2.1M vs 8.4M global atomics).
#define BB 16
#define NN 2048
#define MM 8192

#define TN 128                 // query rows per block (4 waves x 32)
#define TM 512                 // ref cols per block (LDS tile 32 KB)
#define BLK 256

typedef __attribute__((ext_vector_type(8))) short short8;
typedef __attribute__((ext_vector_type(4))) float f32x4;

union U16 { uint4 u; short8 s; };

// ---- bf16 3-way split helpers (round-to-nearest-even) ----
static __device__ __forceinline__ unsigned short f2bf(float f) {
    unsigned int u = __float_as_uint(f);
    unsigned int r = (u + 0x7FFFu + ((u >> 16) & 1u)) >> 16;
    return (unsigned short)r;
}
static __device__ __forceinline__ float bf2f(unsigned short h) {
    return __uint_as_float(((unsigned int)h) << 16);
}

// ws layout:
//   ws2 : uint[BB*MM]        ref->samp mins (atomicMin, memset 0x7F)  512 KB
//   ws1 : uint[BB*NN]        samp->ref mins (atomicMin, memset 0x7F)  128 KB
//   Apk : ushort[BB*NN*32]   query K-major bf16 frags (64 B/point)      2 MB
//   Bpk : ushort[BB*MM*32]   ref K-major bf16 frags, chunk-swizzled     8 MB

// Build the packed K-layouts. A groups: {1,1,2,1,3,2}; B groups: {1,2,1,3,1,2}.
// B chunks (16B) are stored at (g ^ ((m>>1)&3)) so a LINEAR global->LDS copy
// yields a bank-conflict-free ds_read_b128 fragment pattern in sweep.
__global__ void __launch_bounds__(BLK) prep_kernel(const float* __restrict__ ref,
                                                   const float* __restrict__ samp,
                                                   unsigned short* __restrict__ Apk,
                                                   unsigned short* __restrict__ Bpk) {
    const int i = blockIdx.x * BLK + threadIdx.x;
    const int PN = BB * NN;
    float a5[5];
    unsigned short h[3][5];
    unsigned short K[32];

    if (i < PN) {
        const float* s0 = samp + (size_t)i * 3;
        float x = s0[0], y = s0[1], z = s0[2];
        a5[0] = x; a5[1] = y; a5[2] = z;
        a5[3] = fmaf(x, x, fmaf(y, y, z * z)); a5[4] = 1.f;
#pragma unroll
        for (int j = 0; j < 5; ++j) {
            float v = a5[j];
            h[0][j] = f2bf(v); float r1 = v - bf2f(h[0][j]);
            h[1][j] = f2bf(r1); float r2 = r1 - bf2f(h[1][j]);
            h[2][j] = f2bf(r2);
        }
        const int ordA[6] = {0, 0, 1, 0, 2, 1};
#pragma unroll
        for (int t = 0; t < 6; ++t)
#pragma unroll
            for (int j = 0; j < 5; ++j) K[t * 5 + j] = h[ordA[t]][j];
        K[30] = 0; K[31] = 0;
        unsigned int uu[16];
#pragma unroll
        for (int t = 0; t < 16; ++t)
            uu[t] = (unsigned int)K[2 * t] | ((unsigned int)K[2 * t + 1] << 16);
        uint4* dst = (uint4*)(Apk + (size_t)i * 32);
        dst[0] = make_uint4(uu[0], uu[1], uu[2], uu[3]);
        dst[1] = make_uint4(uu[4], uu[5], uu[6], uu[7]);
        dst[2] = make_uint4(uu[8], uu[9], uu[10], uu[11]);
        dst[3] = make_uint4(uu[12], uu[13], uu[14], uu[15]);
    } else if (i < PN + BB * MM) {
        const int j = i - PN;
        const int m = j & (MM - 1);
        const float* r0 = ref + (size_t)j * 3;
        float x = r0[0], y = r0[1], z = r0[2];
        a5[0] = -2.f * x; a5[1] = -2.f * y; a5[2] = -2.f * z;
        a5[3] = 1.f; a5[4] = fmaf(x, x, fmaf(y, y, z * z));
#pragma unroll
        for (int jj = 0; jj < 5; ++jj) {
            float v = a5[jj];
            h[0][jj] = f2bf(v); float r1 = v - bf2f(h[0][jj]);
            h[1][jj] = f2bf(r1); float r2 = r1 - bf2f(h[1][jj]);
            h[2][jj] = f2bf(r2);
        }
        const int ordB[6] = {0, 1, 0, 2, 0, 1};
#pragma unroll
        for (int t = 0; t < 6; ++t)
#pragma unroll
            for (int jj = 0; jj < 5; ++jj) K[t * 5 + jj] = h[ordB[t]][jj];
        K[30] = 0; K[31] = 0;
        unsigned int uu[16];
#pragma unroll
        for (int t = 0; t < 16; ++t)
            uu[t] = (unsigned int)K[2 * t] | ((unsigned int)K[2 * t + 1] << 16);
        uint4 c0 = make_uint4(uu[0], uu[1], uu[2], uu[3]);
        uint4 c1 = make_uint4(uu[4], uu[5], uu[6], uu[7]);
        uint4 c2 = make_uint4(uu[8], uu[9], uu[10], uu[11]);
        uint4 c3 = make_uint4(uu[12], uu[13], uu[14], uu[15]);
        uint4* dst = (uint4*)(Bpk + (size_t)j * 32);
        const int s = (m >> 1) & 3;                       // bank-quad swizzle
        dst[0 ^ s] = c0; dst[1 ^ s] = c1; dst[2 ^ s] = c2; dst[3 ^ s] = c3;
    }
}

// grid = (B, N/TN, M/TM) = (16,16,16) = 4096 blocks, 4 waves.
// Wave w: rows [n0+32w, n0+32w+32) x all TM cols. Inner loop per 16-col tile:
// 1 ds_read_b128 + 2 MFMA + register mins + 1 fire-and-forget LDS atomicMin.
__global__ void __launch_bounds__(BLK, 4) sweep_kernel(const unsigned short* __restrict__ Apk,
                                                       const unsigned short* __restrict__ Bpk,
                                                       unsigned int* __restrict__ ws2,
                                                       unsigned int* __restrict__ ws1) {
    __shared__ uint4 Bt[TM * 4];                          // 32 KB ref tile
    __shared__ unsigned int colMin[TM];                   // 2 KB per-block col mins

    const int b = blockIdx.x;
    const int n0 = blockIdx.y * TN;
    const int m0 = blockIdx.z * TM;
    const int tid = threadIdx.x;
    const int w = tid >> 6;
    const int l = tid & 63;
    const int r = l & 15;                                 // frag row/col lane
    const int g = l >> 4;                                 // k-octet group

    // stage B tile (linear copy; swizzle already baked into Bpk) + init colMin
    const uint4* bs = (const uint4*)(Bpk + ((size_t)(b * MM + m0)) * 32);
#pragma unroll
    for (int k = 0; k < (TM * 4) / BLK; ++k) Bt[tid + k * BLK] = bs[tid + k * BLK];
    colMin[tid] = 0x7F7F7F7Fu;
    colMin[tid + BLK] = 0x7F7F7F7Fu;

    // A fragments direct from global (L2-hot, coalesced)
    const uint4* ap = (const uint4*)(Apk + ((size_t)(b * NN + n0 + w * 32)) * 32);
    U16 a0, a1;
    a0.u = ap[(r << 2) + g];
    a1.u = ap[64 + (r << 2) + g];
    __syncthreads();

    float qa0 = INFINITY, qa1 = INFINITY, qa2 = INFINITY, qa3 = INFINITY;
    float qb0 = INFINITY, qb1 = INFINITY, qb2 = INFINITY, qb3 = INFINITY;

    const uint4* bp = Bt + (r << 2) + (g ^ ((r >> 1) & 3));   // conflict-free
    const f32x4 fz = {0.f, 0.f, 0.f, 0.f};

#pragma unroll 4
    for (int ct = 0; ct < TM / 16; ++ct) {
        U16 bu; bu.u = bp[ct * 64];                       // ds_read_b128
        f32x4 d0 = __builtin_amdgcn_mfma_f32_16x16x32_bf16(a0.s, bu.s, fz, 0, 0, 0);
        f32x4 d1 = __builtin_amdgcn_mfma_f32_16x16x32_bf16(a1.s, bu.s, fz, 0, 0, 0);
        // query-direction running mins (register-local chains)
        qa0 = fminf(qa0, d0[0]); qa1 = fminf(qa1, d0[1]);
        qa2 = fminf(qa2, d0[2]); qa3 = fminf(qa3, d0[3]);
        qb0 = fminf(qb0, d1[0]); qb1 = fminf(qb1, d1[1]);
        qb2 = fminf(qb2, d1[2]); qb3 = fminf(qb3, d1[3]);
        // ref-direction: in-lane min over this lane's 8 rows, then
        // fire-and-forget LDS atomic (merges g-groups + waves; no dep chain)
        float rm = fminf(fminf(fminf(d0[0], d0[1]), fminf(d0[2], d0[3])),
                         fminf(fminf(d1[0], d1[1]), fminf(d1[2], d1[3])));
        atomicMin(&colMin[ct * 16 + r], __float_as_uint(fmaxf(rm, 0.f)));
    }
    __syncthreads();

    // ref-direction epilogue: one global atomic per col per block
    unsigned int* w2 = ws2 + (size_t)b * MM + m0;
    atomicMin(&w2[tid],       colMin[tid]);
    atomicMin(&w2[tid + BLK], colMin[tid + BLK]);

    // query-direction: combine across the 16 col-lanes, then atomicMin
#pragma unroll
    for (int s = 1; s <= 8; s <<= 1) {
        qa0 = fminf(qa0, __shfl_xor(qa0, s));
        qa1 = fminf(qa1, __shfl_xor(qa1, s));
        qa2 = fminf(qa2, __shfl_xor(qa2, s));
        qa3 = fminf(qa3, __shfl_xor(qa3, s));
        qb0 = fminf(qb0, __shfl_xor(qb0, s));
        qb1 = fminf(qb1, __shfl_xor(qb1, s));
        qb2 = fminf(qb2, __shfl_xor(qb2, s));
        qb3 = fminf(qb3, __shfl_xor(qb3, s));
    }
    if (r == 0) {
        unsigned int* w1 = ws1 + (size_t)b * NN + n0 + w * 32 + g * 4;
        atomicMin(&w1[0],  __float_as_uint(fmaxf(qa0, 0.f)));
        atomicMin(&w1[1],  __float_as_uint(fmaxf(qa1, 0.f)));
        atomicMin(&w1[2],  __float_as_uint(fmaxf(qa2, 0.f)));
        atomicMin(&w1[3],  __float_as_uint(fmaxf(qa3, 0.f)));
        atomicMin(&w1[16], __float_as_uint(fmaxf(qb0, 0.f)));
        atomicMin(&w1[17], __float_as_uint(fmaxf(qb1, 0.f)));
        atomicMin(&w1[18], __float_as_uint(fmaxf(qb2, 0.f)));
        atomicMin(&w1[19], __float_as_uint(fmaxf(qb3, 0.f)));
    }
}

// Final reduce. grid = B, block = 1024. Wave shuffle-reduce + one LDS pass.
#define BLKR 1024
__global__ void __launch_bounds__(BLKR) reduce_kernel(const unsigned int* __restrict__ ws1,
                                                      const unsigned int* __restrict__ ws2,
                                                      float* __restrict__ out) {
    const int b = blockIdx.x;
    const int tid = threadIdx.x;
    const int lane = tid & 63;
    const int wv = tid >> 6;

    float sd1 = 0.f, sr1 = 0.f, sd2 = 0.f, sr2 = 0.f;
#pragma unroll
    for (int i = tid; i < NN; i += BLKR) {
        float v = __uint_as_float(ws1[(size_t)b * NN + i]);  // already >= 0
        sd1 += v;
        sr1 += sqrtf(v);
    }
#pragma unroll
    for (int i = tid; i < MM; i += BLKR) {
        float v = __uint_as_float(ws2[(size_t)b * MM + i]);  // already >= 0
        sd2 += v;
        sr2 += sqrtf(v);
    }
#pragma unroll
    for (int s = 32; s > 0; s >>= 1) {
        sd1 += __shfl_xor(sd1, s);
        sr1 += __shfl_xor(sr1, s);
        sd2 += __shfl_xor(sd2, s);
        sr2 += __shfl_xor(sr2, s);
    }

    __shared__ float4 red[BLKR / 64];
    if (lane == 0) red[wv] = make_float4(sd1, sr1, sd2, sr2);
    __syncthreads();
    if (tid == 0) {
        float4 acc = red[0];
#pragma unroll
        for (int w = 1; w < BLKR / 64; ++w) {
            acc.x += red[w].x; acc.y += red[w].y;
            acc.z += red[w].z; acc.w += red[w].w;
        }
        out[b]      = (acc.y * (1.0f / NN) + acc.w * (1.0f / MM)) * 0.5f;  // cd_p
        out[BB + b] = acc.x * (1.0f / NN) + acc.z * (1.0f / MM);           // cd_t
    }
}

extern "C" void kernel_launch(void* const* d_in, const int* in_sizes, int n_in,
                              void* d_out, int out_size, void* d_ws, size_t ws_size,
                              hipStream_t stream) {
    const float* ref  = (const float*)d_in[0];   // [B, M, 3]
    const float* samp = (const float*)d_in[1];   // [B, N, 3]
    float* out = (float*)d_out;                  // [cd_p[16], cd_t[16]]

    unsigned int* ws2 = (unsigned int*)d_ws;                        // BB*MM
    unsigned int* ws1 = ws2 + (size_t)BB * MM;                      // BB*NN
    unsigned short* Apk = (unsigned short*)(ws1 + (size_t)BB * NN); // BB*NN*32
    unsigned short* Bpk = Apk + (size_t)BB * NN * 32;               // BB*MM*32

    // 0x7F7F7F7F = 3.39e38 as float: +inf stand-in for uint-ordered atomicMin
    // over non-negative float bit patterns.
    hipMemsetAsync(d_ws, 0x7F, ((size_t)BB * MM + (size_t)BB * NN) * sizeof(unsigned int), stream);

    const int P = BB * (NN + MM);
    prep_kernel<<<P / BLK, BLK, 0, stream>>>(ref, samp, Apk, Bpk);

    dim3 gs(BB, NN / TN, MM / TM);   // (16, 16, 16) = 4096 blocks
    sweep_kernel<<<gs, BLK, 0, stream>>>(Apk, Bpk, ws2, ws1);

    reduce_kernel<<<BB, BLKR, 0, stream>>>(ws1, ws2, out);
}

// Round 5
// 96.317 us; speedup vs baseline: 1.7683x; 1.0703x over previous
//
#include <hip/hip_runtime.h>
#include <math.h>

// Chamfer distance via MFMA: d2[m,n] = r(m)·q(n), augmented 5-vectors
//   r = (-2px,-2py,-2pz,|p|^2,1)  [A, resident refs]
//   q = (qx,qy,qz,1,|q|^2)        [B, streamed queries]
// fp32 precision via 3-way bf16 split (r=r1+r2+r3, q=q1+q2+q3), products
// {11,12,21,13,31,22} packed along K: 2 chained v_mfma_f32_32x32x16_bf16
// per 32x32 tile (frag0 = groups {11,12,21}, frag1 = {13,31,22}; slot 15/31 = 0).
// B=16, N=2048 samp, M=8192 ref, fp32 in/out.
//
// v6 vs v5 (103 us; sweep 43 us, no pipe >43% busy):
//  - 32x32 tiles, 64 refs resident/wave (2 row-tiles): 2048 dists per
//    {2 ds_read_b128 + 4 MFMA + 1 two-way LDS atomic} -> 4x fewer, fatter iters.
//  - refs partitioned per block -> ws2 plain stores (no atomics, no init);
//    ref mins merged once/block via DPP butterfly (VALU) + ds_swizzle xor16.
//  - queries double-buffer-staged via global_load_lds (zero-VGPR prefetch).
//  - memset dispatch deleted (ws1 init folded into prep).
#define BB 16
#define NN 2048
#define MM 8192

#define BLK 256
#define QSTG 512               // queries per stage (32 KB)
#define NSTAGE (NN / QSTG)     // 4
#define CTS (QSTG / 32)        // 16 col-tiles per stage

typedef __attribute__((ext_vector_type(8))) short short8;
typedef __attribute__((ext_vector_type(16))) float f32x16;

union U16 { uint4 u; short8 s; };

static __device__ __forceinline__ unsigned short f2bf(float f) {
    unsigned int u = __float_as_uint(f);
    unsigned int r = (u + 0x7FFFu + ((u >> 16) & 1u)) >> 16;
    return (unsigned short)r;
}
static __device__ __forceinline__ float bf2f(unsigned short h) {
    return __uint_as_float(((unsigned int)h) << 16);
}

static __device__ __forceinline__ void glds16(const uint4* g, uint4* l) {
    __builtin_amdgcn_global_load_lds(
        (const __attribute__((address_space(1))) unsigned int*)g,
        (__attribute__((address_space(3))) unsigned int*)l,
        16, 0, 0);
}

// DPP-min butterfly steps (all VALU; merge within 16-lane rows)
#define DPP_MIN(v, CTRL)                                                      \
    v = fminf(v, __uint_as_float((unsigned)__builtin_amdgcn_update_dpp(       \
                     0, (int)__float_as_uint(v), CTRL, 0xF, 0xF, true)))
#define SWZ16_MIN(v)                                                          \
    v = fminf(v, __uint_as_float((unsigned)__builtin_amdgcn_ds_swizzle(       \
                     (int)__float_as_uint(v), 0x401F)))

// ws layout:
//   ws2 : float[BB*MM]       ref->samp mins (plain stores)          512 KB
//   ws1 : uint[BB*NN]        samp->ref mins (atomicMin, prep-init)  128 KB
//   Qpk : ushort[BB*NN*32]   query frags, chunk-swizzled              2 MB
//   Rpk : ushort[BB*MM*32]   ref frags, plain chunk order             8 MB

__global__ void __launch_bounds__(BLK) prep_kernel(const float* __restrict__ ref,
                                                   const float* __restrict__ samp,
                                                   unsigned short* __restrict__ Qpk,
                                                   unsigned short* __restrict__ Rpk,
                                                   unsigned int* __restrict__ ws1) {
    const int i = blockIdx.x * BLK + threadIdx.x;
    const int PN = BB * NN;
    float a5[5];
    unsigned short h[3][5];
    unsigned short K[32];

    if (i < PN) {
        const float* s0 = samp + (size_t)i * 3;
        float x = s0[0], y = s0[1], z = s0[2];
        a5[0] = x; a5[1] = y; a5[2] = z;
        a5[3] = 1.f; a5[4] = fmaf(x, x, fmaf(y, y, z * z));
#pragma unroll
        for (int j = 0; j < 5; ++j) {
            float v = a5[j];
            h[0][j] = f2bf(v); float r1 = v - bf2f(h[0][j]);
            h[1][j] = f2bf(r1); float r2 = r1 - bf2f(h[1][j]);
            h[2][j] = f2bf(r2);
        }
        const int ordQ[6] = {0, 1, 0, 2, 0, 1};   // B-side levels per group
#pragma unroll
        for (int f = 0; f < 2; ++f) {
#pragma unroll
            for (int p2 = 0; p2 < 3; ++p2)
#pragma unroll
                for (int j2 = 0; j2 < 5; ++j2)
                    K[f * 16 + p2 * 5 + j2] = h[ordQ[f * 3 + p2]][j2];
            K[f * 16 + 15] = 0;
        }
        unsigned int uu[16];
#pragma unroll
        for (int t = 0; t < 16; ++t)
            uu[t] = (unsigned int)K[2 * t] | ((unsigned int)K[2 * t + 1] << 16);
        uint4 c0 = make_uint4(uu[0], uu[1], uu[2], uu[3]);
        uint4 c1 = make_uint4(uu[4], uu[5], uu[6], uu[7]);
        uint4 c2 = make_uint4(uu[8], uu[9], uu[10], uu[11]);
        uint4 c3 = make_uint4(uu[12], uu[13], uu[14], uu[15]);
        uint4* dst = (uint4*)(Qpk + (size_t)i * 32);
        const int sw = (i >> 1) & 3;              // bank-granule swizzle
        dst[0 ^ sw] = c0; dst[1 ^ sw] = c1; dst[2 ^ sw] = c2; dst[3 ^ sw] = c3;
        ws1[i] = 0x7F7F7F7Fu;                     // +inf stand-in (nonneg floats)
    } else if (i < PN + BB * MM) {
        const int j = i - PN;
        const float* r0 = ref + (size_t)j * 3;
        float x = r0[0], y = r0[1], z = r0[2];
        a5[0] = -2.f * x; a5[1] = -2.f * y; a5[2] = -2.f * z;
        a5[3] = fmaf(x, x, fmaf(y, y, z * z)); a5[4] = 1.f;
#pragma unroll
        for (int jj = 0; jj < 5; ++jj) {
            float v = a5[jj];
            h[0][jj] = f2bf(v); float r1 = v - bf2f(h[0][jj]);
            h[1][jj] = f2bf(r1); float r2 = r1 - bf2f(h[1][jj]);
            h[2][jj] = f2bf(r2);
        }
        const int ordR[6] = {0, 0, 1, 0, 2, 1};   // A-side levels per group
#pragma unroll
        for (int f = 0; f < 2; ++f) {
#pragma unroll
            for (int p2 = 0; p2 < 3; ++p2)
#pragma unroll
                for (int j2 = 0; j2 < 5; ++j2)
                    K[f * 16 + p2 * 5 + j2] = h[ordR[f * 3 + p2]][j2];
            K[f * 16 + 15] = 0;
        }
        unsigned int uu[16];
#pragma unroll
        for (int t = 0; t < 16; ++t)
            uu[t] = (unsigned int)K[2 * t] | ((unsigned int)K[2 * t + 1] << 16);
        uint4* dst = (uint4*)(Rpk + (size_t)j * 32);
        dst[0] = make_uint4(uu[0], uu[1], uu[2], uu[3]);
        dst[1] = make_uint4(uu[4], uu[5], uu[6], uu[7]);
        dst[2] = make_uint4(uu[8], uu[9], uu[10], uu[11]);
        dst[3] = make_uint4(uu[12], uu[13], uu[14], uu[15]);
    }
}

// grid = (B, M/256) = (16, 32) = 512 blocks, 4 waves. Wave owns 64 refs
// (2 row-tiles of 32); streams all 2048 queries in 4 double-buffered stages.
// D layout (verified): col = lane&31 (query), row = (reg&3)+8*(reg>>2)+4*(lane>>5).
__global__ void __launch_bounds__(BLK, 4) sweep_kernel(const unsigned short* __restrict__ Qpk,
                                                       const unsigned short* __restrict__ Rpk,
                                                       float* __restrict__ ws2,
                                                       unsigned int* __restrict__ ws1) {
    __shared__ uint4 Qt[2][QSTG * 4];             // 64 KB double-buffered stage
    __shared__ unsigned int qMin[NN];             // 8 KB

    const int b = blockIdx.x;
    const int m0 = blockIdx.y * 256;
    const int tid = threadIdx.x;
    const int w = tid >> 6;
    const int l = tid & 63;
    const int p = l & 31;                         // col lane (query within ct)
    const int kh = l >> 5;                        // k-half

    // resident A fragments: 64 refs (2 tiles), 2 K-frags each
    const uint4* R4 = (const uint4*)Rpk + ((size_t)(b * MM + m0 + w * 64 + p)) * 4;
    U16 a0f0, a0f1, a1f0, a1f1;
    a0f0.u = R4[kh];        a0f1.u = R4[2 + kh];
    a1f0.u = R4[128 + kh];  a1f1.u = R4[128 + 2 + kh];

    for (int i = tid; i < NN; i += BLK) qMin[i] = 0x7F7F7F7Fu;

    const uint4* Q4 = (const uint4*)Qpk + (size_t)b * (NN * 4);
    {   // stage 0 load
        uint4* dst = &Qt[0][0];
#pragma unroll
        for (int k = 0; k < 8; ++k) glds16(Q4 + k * BLK + tid, dst + k * BLK + tid);
    }
    __syncthreads();

    float run0[16], run1[16];
#pragma unroll
    for (int j = 0; j < 16; ++j) { run0[j] = INFINITY; run1[j] = INFINITY; }

    const int sw = (p >> 1) & 3;
    const f32x16 fz = {0.f, 0.f, 0.f, 0.f, 0.f, 0.f, 0.f, 0.f,
                       0.f, 0.f, 0.f, 0.f, 0.f, 0.f, 0.f, 0.f};

    for (int st = 0; st < NSTAGE; ++st) {
        const uint4* qb = &Qt[st & 1][0];
        if (st < NSTAGE - 1) {                    // prefetch next stage
            const uint4* src = Q4 + (size_t)(st + 1) * (QSTG * 4);
            uint4* dst = &Qt[(st + 1) & 1][0];
#pragma unroll
            for (int k = 0; k < 8; ++k) glds16(src + k * BLK + tid, dst + k * BLK + tid);
        }
#pragma unroll 2
        for (int ct = 0; ct < CTS; ++ct) {
            const int pg = (ct * 32 + p) * 4;
            U16 b0, b1;
            b0.u = qb[pg + (kh ^ sw)];            // ds_read_b128, conflict-free
            b1.u = qb[pg + ((2 + kh) ^ sw)];
            f32x16 d0 = __builtin_amdgcn_mfma_f32_32x32x16_bf16(a0f0.s, b0.s, fz, 0, 0, 0);
            d0 = __builtin_amdgcn_mfma_f32_32x32x16_bf16(a0f1.s, b1.s, d0, 0, 0, 0);
            f32x16 d1 = __builtin_amdgcn_mfma_f32_32x32x16_bf16(a1f0.s, b0.s, fz, 0, 0, 0);
            d1 = __builtin_amdgcn_mfma_f32_32x32x16_bf16(a1f1.s, b1.s, d1, 0, 0, 0);
            // ref-direction running mins (register-local)
#pragma unroll
            for (int j = 0; j < 16; ++j) {
                run0[j] = fminf(run0[j], d0[j]);
                run1[j] = fminf(run1[j], d1[j]);
            }
            // query-direction: tree over this lane's 32 rows -> 2-way LDS atomic
            float tv[8];
#pragma unroll
            for (int k = 0; k < 8; ++k) tv[k] = fminf(d0[k], d0[k + 8]);
#pragma unroll
            for (int k = 0; k < 8; ++k) tv[k] = fminf(tv[k], fminf(d1[k], d1[k + 8]));
#pragma unroll
            for (int k = 0; k < 4; ++k) tv[k] = fminf(tv[k], tv[k + 4]);
            float t = fminf(fminf(tv[0], tv[2]), fminf(tv[1], tv[3]));
            atomicMin(&qMin[st * QSTG + ct * 32 + p], __float_as_uint(fmaxf(t, 0.f)));
        }
        __syncthreads();
    }

    // query-direction dump: one global atomicMin per query per block
#pragma unroll
    for (int i = tid; i < NN; i += BLK)
        atomicMin(&ws1[(size_t)b * NN + i], qMin[i]);

    // ref-direction merge across the 32 lanes of each half: DPP butterfly
#pragma unroll
    for (int j = 0; j < 16; ++j) {
        DPP_MIN(run0[j], 0xB1);  DPP_MIN(run0[j], 0x4E);   // quad_perm xor1, xor2
        DPP_MIN(run0[j], 0x141); DPP_MIN(run0[j], 0x140);  // half_mirror, mirror
        SWZ16_MIN(run0[j]);                                // lane ^ 16
        DPP_MIN(run1[j], 0xB1);  DPP_MIN(run1[j], 0x4E);
        DPP_MIN(run1[j], 0x141); DPP_MIN(run1[j], 0x140);
        SWZ16_MIN(run1[j]);
    }
    // lane (p = t*16+j) takes run_t[j]; row = t*32 + (j&3) + 8*(j>>2) + 4*kh
    float out = 0.f;
#pragma unroll
    for (int j = 0; j < 16; ++j) { if (p == j)      out = run0[j]; }
#pragma unroll
    for (int j = 0; j < 16; ++j) { if (p == 16 + j) out = run1[j]; }
    const int t2 = p >> 4, j4 = p & 15;
    const int row = t2 * 32 + (j4 & 3) + ((j4 >> 2) << 3) + 4 * kh;
    ws2[(size_t)b * MM + m0 + w * 64 + row] = fmaxf(out, 0.f);
}

// Final reduce. grid = B, block = 1024.
#define BLKR 1024
__global__ void __launch_bounds__(BLKR) reduce_kernel(const unsigned int* __restrict__ ws1,
                                                      const float* __restrict__ ws2,
                                                      float* __restrict__ out) {
    const int b = blockIdx.x;
    const int tid = threadIdx.x;
    const int lane = tid & 63;
    const int wv = tid >> 6;

    float sd1 = 0.f, sr1 = 0.f, sd2 = 0.f, sr2 = 0.f;
#pragma unroll
    for (int i = tid; i < NN; i += BLKR) {
        float v = __uint_as_float(ws1[(size_t)b * NN + i]);
        sd1 += v;
        sr1 += sqrtf(v);
    }
#pragma unroll
    for (int i = tid; i < MM; i += BLKR) {
        float v = ws2[(size_t)b * MM + i];
        sd2 += v;
        sr2 += sqrtf(v);
    }
#pragma unroll
    for (int s = 32; s > 0; s >>= 1) {
        sd1 += __shfl_xor(sd1, s);
        sr1 += __shfl_xor(sr1, s);
        sd2 += __shfl_xor(sd2, s);
        sr2 += __shfl_xor(sr2, s);
    }

    __shared__ float4 red[BLKR / 64];
    if (lane == 0) red[wv] = make_float4(sd1, sr1, sd2, sr2);
    __syncthreads();
    if (tid == 0) {
        float4 acc = red[0];
#pragma unroll
        for (int w = 1; w < BLKR / 64; ++w) {
            acc.x += red[w].x; acc.y += red[w].y;
            acc.z += red[w].z; acc.w += red[w].w;
        }
        out[b]      = (acc.y * (1.0f / NN) + acc.w * (1.0f / MM)) * 0.5f;  // cd_p
        out[BB + b] = acc.x * (1.0f / NN) + acc.z * (1.0f / MM);           // cd_t
    }
}

extern "C" void kernel_launch(void* const* d_in, const int* in_sizes, int n_in,
                              void* d_out, int out_size, void* d_ws, size_t ws_size,
                              hipStream_t stream) {
    const float* ref  = (const float*)d_in[0];   // [B, M, 3]
    const float* samp = (const float*)d_in[1];   // [B, N, 3]
    float* out = (float*)d_out;                  // [cd_p[16], cd_t[16]]

    float* ws2 = (float*)d_ws;                                       // BB*MM
    unsigned int* ws1 = (unsigned int*)(ws2 + (size_t)BB * MM);      // BB*NN
    unsigned short* Qpk = (unsigned short*)(ws1 + (size_t)BB * NN);  // BB*NN*32
    unsigned short* Rpk = Qpk + (size_t)BB * NN * 32;                // BB*MM*32

    const int P = BB * (NN + MM);
    prep_kernel<<<P / BLK, BLK, 0, stream>>>(ref, samp, Qpk, Rpk, ws1);

    dim3 gs(BB, MM / 256);   // (16, 32) = 512 blocks
    sweep_kernel<<<gs, BLK, 0, stream>>>(Qpk, Rpk, ws2, ws1);

    reduce_kernel<<<BB, BLKR, 0, stream>>>(ws1, ws2, out);
}

// Round 6
// 89.177 us; speedup vs baseline: 1.9099x; 1.0801x over previous
//
#include <hip/hip_runtime.h>
#include <math.h>

// Chamfer distance via MFMA: d2[m,n] = r(m)·q(n), augmented 5-vectors
//   r = (-2px,-2py,-2pz,|p|^2,1)  [A, resident refs]
//   q = (qx,qy,qz,1,|q|^2)        [B, streamed queries]
// fp32 precision via 3-way bf16 split (r=r1+r2+r3, q=q1+q2+q3), products
// {11,12,21,13,31,22} packed along K: 2 chained v_mfma_f32_32x32x16_bf16
// per 32x32 tile. Verified absmax = 0.0 (bit-exact vs fp32 reference).
// B=16, N=2048 samp, M=8192 ref, fp32 in/out.
//
// v7 vs v6 (96.3 us; ~42 us of that is the harness workspace-poison fill —
// unavoidable floor; sweep grid-capped at 2 blocks/CU = 2 waves/SIMD):
//  - query-split grid (16,32,2) = 1024 blocks, 1024 queries/block in 4
//    stages of 256: 4 blocks/CU, 4 waves/SIMD, LDS 72->36 KB.
//  - ref-prep fused into sweep (block preps its own 256 refs into the Qt[1]
//    buffer before the stream loop); prep kernel now queries-only (33K pts).
//  - ws1 global atomics -> plain-store partials ws1p[32][B][N], min-folded
//    in reduce; ws2 -> 2-way partials ws2p[2][B][M].
#define BB 16
#define NN 2048
#define MM 8192

#define BLK 256
#define QSPL 2                 // query splits
#define NQ (NN / QSPL)         // 1024 queries per block
#define QSTG 256               // queries per stage (16 KB)
#define NSTAGE (NQ / QSTG)     // 4
#define CTS (QSTG / 32)        // 8 col-tiles per stage
#define YB (MM / 256)          // 32 ref blocks (ws1 partials)

typedef __attribute__((ext_vector_type(8))) short short8;
typedef __attribute__((ext_vector_type(16))) float f32x16;

union U16 { uint4 u; short8 s; };

static __device__ __forceinline__ unsigned short f2bf(float f) {
    unsigned int u = __float_as_uint(f);
    unsigned int r = (u + 0x7FFFu + ((u >> 16) & 1u)) >> 16;
    return (unsigned short)r;
}
static __device__ __forceinline__ float bf2f(unsigned short h) {
    return __uint_as_float(((unsigned int)h) << 16);
}

static __device__ __forceinline__ void glds16(const uint4* g, uint4* l) {
    __builtin_amdgcn_global_load_lds(
        (const __attribute__((address_space(1))) unsigned int*)g,
        (__attribute__((address_space(3))) unsigned int*)l,
        16, 0, 0);
}

// DPP-min butterfly steps (all VALU; merge within 32-lane halves)
#define DPP_MIN(v, CTRL)                                                      \
    v = fminf(v, __uint_as_float((unsigned)__builtin_amdgcn_update_dpp(       \
                     0, (int)__float_as_uint(v), CTRL, 0xF, 0xF, true)))
#define SWZ16_MIN(v)                                                          \
    v = fminf(v, __uint_as_float((unsigned)__builtin_amdgcn_ds_swizzle(       \
                     (int)__float_as_uint(v), 0x401F)))

// ws layout:
//   ws2p : float[QSPL*BB*MM]  ref->samp partial mins (plain stores)    1 MB
//   ws1p : float[YB*BB*NN]    samp->ref partial mins (plain stores)    4 MB
//   Qpk  : ushort[BB*NN*32]   query frags, chunk-swizzled              2 MB

// Queries-only prep: 3-way split + K-pack + bank-granule chunk swizzle.
__global__ void __launch_bounds__(BLK) prep_kernel(const float* __restrict__ samp,
                                                   unsigned short* __restrict__ Qpk) {
    const int i = blockIdx.x * BLK + threadIdx.x;   // < BB*NN
    const float* s0 = samp + (size_t)i * 3;
    float x = s0[0], y = s0[1], z = s0[2];
    float a5[5];
    a5[0] = x; a5[1] = y; a5[2] = z;
    a5[3] = 1.f; a5[4] = fmaf(x, x, fmaf(y, y, z * z));
    unsigned short h[3][5];
#pragma unroll
    for (int j = 0; j < 5; ++j) {
        float v = a5[j];
        h[0][j] = f2bf(v); float r1 = v - bf2f(h[0][j]);
        h[1][j] = f2bf(r1); float r2 = r1 - bf2f(h[1][j]);
        h[2][j] = f2bf(r2);
    }
    const int ordQ[6] = {0, 1, 0, 2, 0, 1};         // B-side levels per group
    unsigned short K[32];
#pragma unroll
    for (int f = 0; f < 2; ++f) {
#pragma unroll
        for (int p2 = 0; p2 < 3; ++p2)
#pragma unroll
            for (int j2 = 0; j2 < 5; ++j2)
                K[f * 16 + p2 * 5 + j2] = h[ordQ[f * 3 + p2]][j2];
        K[f * 16 + 15] = 0;
    }
    unsigned int uu[16];
#pragma unroll
    for (int t = 0; t < 16; ++t)
        uu[t] = (unsigned int)K[2 * t] | ((unsigned int)K[2 * t + 1] << 16);
    uint4* dst = (uint4*)(Qpk + (size_t)i * 32);
    const int sw = (i >> 1) & 3;                    // bank-granule swizzle
    dst[0 ^ sw] = make_uint4(uu[0], uu[1], uu[2], uu[3]);
    dst[1 ^ sw] = make_uint4(uu[4], uu[5], uu[6], uu[7]);
    dst[2 ^ sw] = make_uint4(uu[8], uu[9], uu[10], uu[11]);
    dst[3 ^ sw] = make_uint4(uu[12], uu[13], uu[14], uu[15]);
}

// grid = (B, M/256, QSPL) = (16,32,2) = 1024 blocks, 4 waves.
// Wave owns 64 refs (2 row-tiles of 32); streams NQ=1024 queries in 4
// double-buffered stages of 256. Ref frags built in-kernel in Qt[1] scratch.
// D layout (verified): col = lane&31 (query), row = (reg&3)+8*(reg>>2)+4*(lane>>5).
__global__ void __launch_bounds__(BLK, 4) sweep_kernel(const float* __restrict__ ref,
                                                       const unsigned short* __restrict__ Qpk,
                                                       float* __restrict__ ws2p,
                                                       float* __restrict__ ws1p) {
    __shared__ uint4 Qt[2][QSTG * 4];             // 32 KB double-buffered stage
    __shared__ unsigned int qMin[NQ];             // 4 KB

    const int b = blockIdx.x;
    const int m0 = blockIdx.y * 256;
    const int q0 = blockIdx.z * NQ;
    const int tid = threadIdx.x;
    const int w = tid >> 6;
    const int l = tid & 63;
    const int p = l & 31;                         // col lane (query within ct)
    const int kh = l >> 5;                        // k-half

    // ---- ref prep: this block's 256 refs -> Qt[1] scratch (chunk-major) ----
    {
        const float* r0 = ref + ((size_t)(b * MM + m0 + tid)) * 3;
        float x = r0[0], y = r0[1], z = r0[2];
        float a5[5];
        a5[0] = -2.f * x; a5[1] = -2.f * y; a5[2] = -2.f * z;
        a5[3] = fmaf(x, x, fmaf(y, y, z * z)); a5[4] = 1.f;
        unsigned short h[3][5];
#pragma unroll
        for (int j = 0; j < 5; ++j) {
            float v = a5[j];
            h[0][j] = f2bf(v); float r1 = v - bf2f(h[0][j]);
            h[1][j] = f2bf(r1); float r2 = r1 - bf2f(h[1][j]);
            h[2][j] = f2bf(r2);
        }
        const int ordR[6] = {0, 0, 1, 0, 2, 1};   // A-side levels per group
        unsigned short K[32];
#pragma unroll
        for (int f = 0; f < 2; ++f) {
#pragma unroll
            for (int p2 = 0; p2 < 3; ++p2)
#pragma unroll
                for (int j2 = 0; j2 < 5; ++j2)
                    K[f * 16 + p2 * 5 + j2] = h[ordR[f * 3 + p2]][j2];
            K[f * 16 + 15] = 0;
        }
        unsigned int uu[16];
#pragma unroll
        for (int t = 0; t < 16; ++t)
            uu[t] = (unsigned int)K[2 * t] | ((unsigned int)K[2 * t + 1] << 16);
        uint4* scr = &Qt[1][0];                   // chunk-major: [c][ref]
        scr[0 * 256 + tid] = make_uint4(uu[0], uu[1], uu[2], uu[3]);
        scr[1 * 256 + tid] = make_uint4(uu[4], uu[5], uu[6], uu[7]);
        scr[2 * 256 + tid] = make_uint4(uu[8], uu[9], uu[10], uu[11]);
        scr[3 * 256 + tid] = make_uint4(uu[12], uu[13], uu[14], uu[15]);
    }
    for (int i = tid; i < NQ; i += BLK) qMin[i] = 0x7F7F7F7Fu;
    __syncthreads();

    // resident A fragments from scratch (2-way conflict reads = free)
    U16 a0f0, a0f1, a1f0, a1f1;
    {
        const uint4* scr = &Qt[1][0];
        a0f0.u = scr[kh * 256 + w * 64 + p];
        a0f1.u = scr[(2 + kh) * 256 + w * 64 + p];
        a1f0.u = scr[kh * 256 + w * 64 + 32 + p];
        a1f1.u = scr[(2 + kh) * 256 + w * 64 + 32 + p];
    }

    const uint4* Q4 = (const uint4*)Qpk + ((size_t)b * NN + q0) * 4;
    {   // stage 0 load (glds; vmcnt drained by the barrier below)
        uint4* dst = &Qt[0][0];
#pragma unroll
        for (int k = 0; k < 4; ++k) glds16(Q4 + k * BLK + tid, dst + k * BLK + tid);
    }
    __syncthreads();    // scratch reads done (all waves) + stage 0 landed

    float run0[16], run1[16];
#pragma unroll
    for (int j = 0; j < 16; ++j) { run0[j] = INFINITY; run1[j] = INFINITY; }

    const int sw = (p >> 1) & 3;
    const f32x16 fz = {0.f, 0.f, 0.f, 0.f, 0.f, 0.f, 0.f, 0.f,
                       0.f, 0.f, 0.f, 0.f, 0.f, 0.f, 0.f, 0.f};

    for (int st = 0; st < NSTAGE; ++st) {
        const uint4* qb = &Qt[st & 1][0];
        if (st < NSTAGE - 1) {                    // prefetch next stage
            const uint4* src = Q4 + (size_t)(st + 1) * (QSTG * 4);
            uint4* dst = &Qt[(st + 1) & 1][0];
#pragma unroll
            for (int k = 0; k < 4; ++k) glds16(src + k * BLK + tid, dst + k * BLK + tid);
        }
#pragma unroll 2
        for (int ct = 0; ct < CTS; ++ct) {
            const int pg = (ct * 32 + p) * 4;
            U16 b0, b1;
            b0.u = qb[pg + (kh ^ sw)];            // ds_read_b128, conflict-free
            b1.u = qb[pg + ((2 + kh) ^ sw)];
            f32x16 d0 = __builtin_amdgcn_mfma_f32_32x32x16_bf16(a0f0.s, b0.s, fz, 0, 0, 0);
            d0 = __builtin_amdgcn_mfma_f32_32x32x16_bf16(a0f1.s, b1.s, d0, 0, 0, 0);
            f32x16 d1 = __builtin_amdgcn_mfma_f32_32x32x16_bf16(a1f0.s, b0.s, fz, 0, 0, 0);
            d1 = __builtin_amdgcn_mfma_f32_32x32x16_bf16(a1f1.s, b1.s, d1, 0, 0, 0);
            // ref-direction running mins (register-local)
#pragma unroll
            for (int j = 0; j < 16; ++j) {
                run0[j] = fminf(run0[j], d0[j]);
                run1[j] = fminf(run1[j], d1[j]);
            }
            // query-direction: tree over this lane's 32 rows -> 2-way LDS atomic
            float tv[8];
#pragma unroll
            for (int k = 0; k < 8; ++k) tv[k] = fminf(d0[k], d0[k + 8]);
#pragma unroll
            for (int k = 0; k < 8; ++k) tv[k] = fminf(tv[k], fminf(d1[k], d1[k + 8]));
#pragma unroll
            for (int k = 0; k < 4; ++k) tv[k] = fminf(tv[k], tv[k + 4]);
            float t = fminf(fminf(tv[0], tv[2]), fminf(tv[1], tv[3]));
            atomicMin(&qMin[st * QSTG + ct * 32 + p], __float_as_uint(fmaxf(t, 0.f)));
        }
        __syncthreads();
    }

    // query-direction dump: plain-store partial per (ref-block, query)
    float* w1 = ws1p + ((size_t)blockIdx.y * BB + b) * NN + q0;
#pragma unroll
    for (int i = tid; i < NQ; i += BLK)
        w1[i] = __uint_as_float(qMin[i]);

    // ref-direction merge across the 32 lanes of each half: DPP butterfly
#pragma unroll
    for (int j = 0; j < 16; ++j) {
        DPP_MIN(run0[j], 0xB1);  DPP_MIN(run0[j], 0x4E);   // quad_perm xor1, xor2
        DPP_MIN(run0[j], 0x141); DPP_MIN(run0[j], 0x140);  // half_mirror, mirror
        SWZ16_MIN(run0[j]);                                // lane ^ 16
        DPP_MIN(run1[j], 0xB1);  DPP_MIN(run1[j], 0x4E);
        DPP_MIN(run1[j], 0x141); DPP_MIN(run1[j], 0x140);
        SWZ16_MIN(run1[j]);
    }
    // lane (p = t*16+j) takes run_t[j]; row = t*32 + (j&3) + 8*(j>>2) + 4*kh
    float out = 0.f;
#pragma unroll
    for (int j = 0; j < 16; ++j) { if (p == j)      out = run0[j]; }
#pragma unroll
    for (int j = 0; j < 16; ++j) { if (p == 16 + j) out = run1[j]; }
    const int t2 = p >> 4, j4 = p & 15;
    const int row = t2 * 32 + (j4 & 3) + ((j4 >> 2) << 3) + 4 * kh;
    ws2p[((size_t)blockIdx.z * BB + b) * MM + m0 + w * 64 + row] = fmaxf(out, 0.f);
}

// Final reduce. grid = B, block = 1024. Min-folds the partials, then sums.
#define BLKR 1024
__global__ void __launch_bounds__(BLKR) reduce_kernel(const float* __restrict__ ws1p,
                                                      const float* __restrict__ ws2p,
                                                      float* __restrict__ out) {
    const int b = blockIdx.x;
    const int tid = threadIdx.x;
    const int lane = tid & 63;
    const int wv = tid >> 6;

    float sd1 = 0.f, sr1 = 0.f, sd2 = 0.f, sr2 = 0.f;
#pragma unroll
    for (int i = tid; i < NN; i += BLKR) {
        float m = INFINITY;
#pragma unroll
        for (int y = 0; y < YB; ++y)
            m = fminf(m, ws1p[((size_t)y * BB + b) * NN + i]);
        sd1 += m;
        sr1 += sqrtf(m);
    }
#pragma unroll
    for (int i = tid; i < MM; i += BLKR) {
        float v = fminf(ws2p[(size_t)b * MM + i],
                        ws2p[((size_t)BB + b) * MM + i]);
        sd2 += v;
        sr2 += sqrtf(v);
    }
#pragma unroll
    for (int s = 32; s > 0; s >>= 1) {
        sd1 += __shfl_xor(sd1, s);
        sr1 += __shfl_xor(sr1, s);
        sd2 += __shfl_xor(sd2, s);
        sr2 += __shfl_xor(sr2, s);
    }

    __shared__ float4 red[BLKR / 64];
    if (lane == 0) red[wv] = make_float4(sd1, sr1, sd2, sr2);
    __syncthreads();
    if (tid == 0) {
        float4 acc = red[0];
#pragma unroll
        for (int w = 1; w < BLKR / 64; ++w) {
            acc.x += red[w].x; acc.y += red[w].y;
            acc.z += red[w].z; acc.w += red[w].w;
        }
        out[b]      = (acc.y * (1.0f / NN) + acc.w * (1.0f / MM)) * 0.5f;  // cd_p
        out[BB + b] = acc.x * (1.0f / NN) + acc.z * (1.0f / MM);           // cd_t
    }
}

extern "C" void kernel_launch(void* const* d_in, const int* in_sizes, int n_in,
                              void* d_out, int out_size, void* d_ws, size_t ws_size,
                              hipStream_t stream) {
    const float* ref  = (const float*)d_in[0];   // [B, M, 3]
    const float* samp = (const float*)d_in[1];   // [B, N, 3]
    float* out = (float*)d_out;                  // [cd_p[16], cd_t[16]]

    float* ws2p = (float*)d_ws;                                        // QSPL*BB*MM
    float* ws1p = ws2p + (size_t)QSPL * BB * MM;                       // YB*BB*NN
    unsigned short* Qpk = (unsigned short*)(ws1p + (size_t)YB * BB * NN);  // BB*NN*32

    prep_kernel<<<(BB * NN) / BLK, BLK, 0, stream>>>(samp, Qpk);

    dim3 gs(BB, MM / 256, QSPL);   // (16, 32, 2) = 1024 blocks
    sweep_kernel<<<gs, BLK, 0, stream>>>(ref, Qpk, ws2p, ws1p);

    reduce_kernel<<<BB, BLKR, 0, stream>>>(ws1p, ws2p, out);
}